// Round 7
// baseline (806.183 us; speedup 1.0000x reference)
//
#include <hip/hip_runtime.h>
#include <hip/hip_bf16.h>
#include <math.h>

#define FDIM 128
#define ODIM 40
#define NBLK 512
#define NTHR 256

typedef __attribute__((ext_vector_type(8))) short bf16x8;
typedef __attribute__((ext_vector_type(4))) float f32x4;

__device__ __forceinline__ float bf_lo(unsigned v) { return __uint_as_float(v << 16); }
__device__ __forceinline__ float bf_hi(unsigned v) { return __uint_as_float(v & 0xFFFF0000u); }
__device__ __forceinline__ unsigned f2bf(float f) {   // round-to-nearest-even
    unsigned u = __float_as_uint(f);
    return (u + 0x7FFFu + ((u >> 16) & 1u)) >> 16;
}

// ---- device-scope grid barrier (all NBLK blocks co-resident by construction)
__device__ __forceinline__ void gsync(unsigned* bar) {
    __syncthreads();
    if (threadIdx.x == 0) {
        __threadfence();                                   // release (device scope)
        unsigned ticket = atomicAdd(bar, 1u);
        unsigned target = (ticket / NBLK + 1u) * NBLK;
        while (__hip_atomic_load(bar, __ATOMIC_RELAXED, __HIP_MEMORY_SCOPE_AGENT) < target)
            __builtin_amdgcn_s_sleep(8);
        __threadfence();                                   // acquire (invalidates this CU's L1)
    }
    __syncthreads();
}

// ---- LDS-free MFMA GEMM phase: Cb[M,128](bf16) = (A[M,128]bf16 @ W)*dinv[row]
// Fragment loads straight from global: A row-major bf16 (16 B/lane contiguous),
// Wt = W^T bf16 [n][k] (same layout as A). L1 absorbs 4x intra-block A reuse.
__device__ __forceinline__ void gemm_phase(const unsigned short* __restrict__ A,
                                           const unsigned short* __restrict__ Wt,
                                           const float* __restrict__ dinv,
                                           unsigned short* __restrict__ Cb, int M) {
    const int tid = threadIdx.x;
    const int lane = tid & 63;
    const int wv = tid >> 6;          // wave 0..3 -> cols wv*32..+31
    const int n0 = wv * 32;
    const int mrow = lane & 15;
    const int quad = lane >> 4;
    const int ntiles = (M + 63) / 64;
    const bf16x8 zz = {0, 0, 0, 0, 0, 0, 0, 0};

    for (int t = blockIdx.x; t < ntiles; t += NBLK) {
        const int row0 = t * 64;
        f32x4 acc[4][2];
#pragma unroll
        for (int mt = 0; mt < 4; ++mt)
#pragma unroll
            for (int nt = 0; nt < 2; ++nt) acc[mt][nt] = (f32x4){0.f, 0.f, 0.f, 0.f};

#pragma unroll
        for (int kk = 0; kk < 128; kk += 32) {
            const int ko = kk + quad * 8;
            bf16x8 af[4], bfr[2];
#pragma unroll
            for (int mt = 0; mt < 4; ++mt) {
                int r = row0 + mt * 16 + mrow;
                af[mt] = (r < M) ? *(const bf16x8*)&A[(size_t)r * 128 + ko] : zz;
            }
#pragma unroll
            for (int nt = 0; nt < 2; ++nt)
                bfr[nt] = *(const bf16x8*)&Wt[(size_t)(n0 + nt * 16 + mrow) * 128 + ko];
#pragma unroll
            for (int mt = 0; mt < 4; ++mt)
#pragma unroll
                for (int nt = 0; nt < 2; ++nt)
                    acc[mt][nt] = __builtin_amdgcn_mfma_f32_16x16x32_bf16(af[mt], bfr[nt], acc[mt][nt], 0, 0, 0);
        }
        // C layout: col=lane&15 (+n0+nt*16), row=quad*4+reg (+row0+mt*16)
#pragma unroll
        for (int mt = 0; mt < 4; ++mt) {
#pragma unroll
            for (int reg = 0; reg < 4; ++reg) {
                int grow = row0 + mt * 16 + quad * 4 + reg;
                if (grow < M) {
                    float sc = dinv[grow];
#pragma unroll
                    for (int nt = 0; nt < 2; ++nt) {
                        int col = n0 + nt * 16 + mrow;
                        Cb[(size_t)grow * 128 + col] = (unsigned short)f2bf(acc[mt][nt][reg] * sc);
                    }
                }
            }
        }
    }
}

// ---- aggregate phase: half-wave (32 lanes) per node, lane = 4 channels (uint2)
template <bool RELU, bool OUT_BF16>
__device__ __forceinline__ void agg_phase(const uint2* __restrict__ g2,
                                          const float* __restrict__ dinv,
                                          const int* __restrict__ rowptr,
                                          const int* __restrict__ csr,
                                          const float* __restrict__ bias,
                                          void* __restrict__ outv, int n) {
    const int tid = threadIdx.x;
    const int h = tid & 31;
    const int slot = blockIdx.x * 8 + (tid >> 5);
    const int nslots = NBLK * 8;
    const float4 bb = ((const float4*)bias)[h];

    for (int d = slot; d < n; d += nslots) {
        uint2 sv = g2[(size_t)d * 32 + h];
        float a0 = bf_lo(sv.x), a1 = bf_hi(sv.x), a2 = bf_lo(sv.y), a3 = bf_hi(sv.y);
        int e = rowptr[d], end = rowptr[d + 1];
        for (; e + 7 < end; e += 8) {
            int s0 = csr[e], s1 = csr[e+1], s2 = csr[e+2], s3 = csr[e+3];
            int s4 = csr[e+4], s5 = csr[e+5], s6 = csr[e+6], s7 = csr[e+7];
            uint2 v0 = g2[(size_t)s0*32+h], v1 = g2[(size_t)s1*32+h];
            uint2 v2 = g2[(size_t)s2*32+h], v3 = g2[(size_t)s3*32+h];
            uint2 v4 = g2[(size_t)s4*32+h], v5 = g2[(size_t)s5*32+h];
            uint2 v6 = g2[(size_t)s6*32+h], v7 = g2[(size_t)s7*32+h];
            a0 += (bf_lo(v0.x)+bf_lo(v1.x)) + (bf_lo(v2.x)+bf_lo(v3.x))
                + (bf_lo(v4.x)+bf_lo(v5.x)) + (bf_lo(v6.x)+bf_lo(v7.x));
            a1 += (bf_hi(v0.x)+bf_hi(v1.x)) + (bf_hi(v2.x)+bf_hi(v3.x))
                + (bf_hi(v4.x)+bf_hi(v5.x)) + (bf_hi(v6.x)+bf_hi(v7.x));
            a2 += (bf_lo(v0.y)+bf_lo(v1.y)) + (bf_lo(v2.y)+bf_lo(v3.y))
                + (bf_lo(v4.y)+bf_lo(v5.y)) + (bf_lo(v6.y)+bf_lo(v7.y));
            a3 += (bf_hi(v0.y)+bf_hi(v1.y)) + (bf_hi(v2.y)+bf_hi(v3.y))
                + (bf_hi(v4.y)+bf_hi(v5.y)) + (bf_hi(v6.y)+bf_hi(v7.y));
        }
        for (; e < end; ++e) {
            uint2 v = g2[(size_t)csr[e] * 32 + h];
            a0 += bf_lo(v.x); a1 += bf_hi(v.x); a2 += bf_lo(v.y); a3 += bf_hi(v.y);
        }
        float sc = dinv[d];
        float o0 = fmaf(sc, a0, bb.x), o1 = fmaf(sc, a1, bb.y);
        float o2 = fmaf(sc, a2, bb.z), o3 = fmaf(sc, a3, bb.w);
        if (RELU) {
            o0 = fmaxf(o0, 0.f); o1 = fmaxf(o1, 0.f);
            o2 = fmaxf(o2, 0.f); o3 = fmaxf(o3, 0.f);
        }
        if constexpr (OUT_BF16) {
            uint2 o;
            o.x = f2bf(o0) | (f2bf(o1) << 16);
            o.y = f2bf(o2) | (f2bf(o3) << 16);
            ((uint2*)outv)[(size_t)d * 32 + h] = o;
        } else {
            ((float4*)outv)[(size_t)d * 32 + h] = make_float4(o0, o1, o2, o3);
        }
    }
}

// ============================ the mega-kernel ==============================
__global__ __launch_bounds__(NTHR, 2) void gcn_mega_k(
        const float* __restrict__ x, const int* __restrict__ src,
        const int* __restrict__ dst,
        const float* __restrict__ W1, const float* __restrict__ b1,
        const float* __restrict__ W2, const float* __restrict__ b2,
        const float* __restrict__ Wl, const float* __restrict__ bl,
        int* count, int* rowptr, int* cursor, int* csr, float* dinv,
        int* chunkSums, unsigned* bar,
        unsigned short* Wt1, unsigned short* Wt2, unsigned short* xbf,
        unsigned short* bufA, unsigned short* bufB,
        float* x_emb, float* out_lsm, int N, int E) {
    __shared__ __align__(16) char smem[37632];   // union: scan ts / logits sW+sB+sX
    const int tid = threadIdx.x;
    const int gthread = blockIdx.x * NTHR + tid;
    const int gstride = NBLK * NTHR;

    // ---- P0: zero counts; Wt = W^T bf16; xbf = bf16(x) ----
    for (int i = gthread; i < N; i += gstride) count[i] = 0;
    for (int i = gthread; i < 2 * 16384; i += gstride) {
        const float* W = (i < 16384) ? W1 : W2;
        unsigned short* Wt = (i < 16384) ? Wt1 : Wt2;
        int j = i & 16383;
        int k = j >> 7, n = j & 127;
        Wt[n * 128 + k] = (unsigned short)f2bf(W[k * 128 + n]);
    }
    for (int i = gthread; i < N * 32; i += gstride) {   // float4 units
        float4 v = ((const float4*)x)[i];
        uint2 o;
        o.x = f2bf(v.x) | (f2bf(v.y) << 16);
        o.y = f2bf(v.z) | (f2bf(v.w) << 16);
        ((uint2*)xbf)[i] = o;
    }
    gsync(bar);

    // ---- P1: count in-degrees ----
    for (int e = gthread; e < E; e += gstride) atomicAdd(&count[dst[e]], 1);
    gsync(bar);

    // ---- P2a: per-chunk sums (CH <= 256) ----
    const int CH = (N + NBLK - 1) / NBLK;               // 98 for N=50000
    int* ts = (int*)smem;
    {
        int base = blockIdx.x * CH;
        int c = 0;
        if (tid < CH && base + tid < N) c = count[base + tid];
        ts[tid] = c;
        __syncthreads();
        for (int off = 128; off > 0; off >>= 1) {
            if (tid < off) ts[tid] += ts[tid + off];
            __syncthreads();
        }
        if (tid == 0) chunkSums[blockIdx.x] = ts[0];
        __syncthreads();
    }
    gsync(bar);

    // ---- P2b: block 0 exclusive-scans the 512 chunk sums ----
    if (blockIdx.x == 0) {
        int s0 = chunkSums[tid * 2], s1 = chunkSums[tid * 2 + 1];
        int ps = s0 + s1;
        ts[tid] = ps;
        __syncthreads();
        for (int off = 1; off < 256; off <<= 1) {
            int v = (tid >= off) ? ts[tid - off] : 0;
            __syncthreads();
            ts[tid] += v;
            __syncthreads();
        }
        int excl = ts[tid] - ps;
        chunkSums[tid * 2] = excl;
        chunkSums[tid * 2 + 1] = excl + s0;
        if (tid == 255) rowptr[N] = ts[255];
    }
    gsync(bar);

    // ---- P2c: local scan + chunk offset -> rowptr/cursor; dinv ----
    {
        int base = blockIdx.x * CH;
        int i = base + tid;
        int c = 0;
        if (tid < CH && i < N) c = count[i];
        ts[tid] = c;
        __syncthreads();
        for (int off = 1; off < 256; off <<= 1) {
            int v = (tid >= off) ? ts[tid - off] : 0;
            __syncthreads();
            ts[tid] += v;
            __syncthreads();
        }
        if (tid < CH && i < N) {
            int excl = ts[tid] - c + chunkSums[blockIdx.x];
            rowptr[i] = excl;
            cursor[i] = excl;
            dinv[i] = rsqrtf((float)(c + 1));
        }
        __syncthreads();
    }
    gsync(bar);

    // ---- P3: fill CSR ----
    for (int e = gthread; e < E; e += gstride) {
        int d = dst[e];
        int p = atomicAdd(&cursor[d], 1);
        csr[p] = src[e];
    }
    gsync(bar);

    // ---- P4: layer-1 GEMM ----
    gemm_phase(xbf, Wt1, dinv, bufA, N);
    gsync(bar);

    // ---- P5: layer-1 aggregate (+bias,+relu) -> bufB bf16 ----
    agg_phase<true, true>((const uint2*)bufA, dinv, rowptr, csr, b1, bufB, N);
    gsync(bar);

    // ---- P6: layer-2 GEMM ----
    gemm_phase(bufB, Wt2, dinv, bufA, N);
    gsync(bar);

    // ---- P7: layer-2 aggregate (+bias) -> x_emb fp32 (d_out) ----
    agg_phase<false, false>((const uint2*)bufA, dinv, rowptr, csr, b2, x_emb, N);
    gsync(bar);

    // ---- P8: logits = x_emb @ Wl + bl; log_softmax(40) ----
    {
        float* sW = (float*)smem;                  // 5120 floats = 20480 B
        float* sB = (float*)(smem + 20480);        // 40 floats
        float* sX = (float*)(smem + 20736);        // 32*132 floats = 16896 B
        for (int i = tid; i < 1280; i += NTHR) ((float4*)sW)[i] = ((const float4*)Wl)[i];
        if (tid < 40) sB[tid] = bl[tid];
        const int g = tid >> 3;
        const int l = tid & 7;
        const int ntile = (N + 31) / 32;
        for (int t = blockIdx.x; t < ntile; t += NBLK) {
            int row0 = t * 32;
            __syncthreads();                       // protect sX reuse
            for (int i = tid; i < 1024; i += NTHR) {
                int r = i >> 5, cq = i & 31;
                float4 v = make_float4(0.f, 0.f, 0.f, 0.f);
                if (row0 + r < N) v = *(const float4*)&x_emb[(size_t)(row0 + r) * 128 + cq * 4];
                *(float4*)&sX[r * 132 + cq * 4] = v;
            }
            __syncthreads();
            int row = row0 + g;
            float acc[5] = {0.f, 0.f, 0.f, 0.f, 0.f};
            for (int k = 0; k < 128; ++k) {
                float xv = sX[g * 132 + k];
                const float* wp = &sW[k * 40 + l * 5];
#pragma unroll
                for (int j = 0; j < 5; ++j) acc[j] = fmaf(xv, wp[j], acc[j]);
            }
#pragma unroll
            for (int j = 0; j < 5; ++j) acc[j] += sB[l * 5 + j];
            float m = acc[0];
#pragma unroll
            for (int j = 1; j < 5; ++j) m = fmaxf(m, acc[j]);
#pragma unroll
            for (int off = 1; off < 8; off <<= 1) m = fmaxf(m, __shfl_xor(m, off));
            float s = 0.f;
#pragma unroll
            for (int j = 0; j < 5; ++j) s += expf(acc[j] - m);
#pragma unroll
            for (int off = 1; off < 8; off <<= 1) s += __shfl_xor(s, off);
            float lse = m + logf(s);
            if (row < N) {
#pragma unroll
                for (int j = 0; j < 5; ++j) out_lsm[(size_t)row * 40 + l * 5 + j] = acc[j] - lse;
            }
        }
    }
}

// ---------------------------------------------------------------------------
extern "C" void kernel_launch(void* const* d_in, const int* in_sizes, int n_in,
                              void* d_out, int out_size, void* d_ws, size_t ws_size,
                              hipStream_t stream) {
    const float* x  = (const float*)d_in[0];
    const int*   ei = (const int*)d_in[1];
    const float* W1 = (const float*)d_in[2];
    const float* b1 = (const float*)d_in[3];
    const float* W2 = (const float*)d_in[4];
    const float* b2 = (const float*)d_in[5];
    const float* Wl = (const float*)d_in[6];
    const float* bl = (const float*)d_in[7];

    const int N = in_sizes[0] / FDIM;   // 50000
    const int E = in_sizes[1] / 2;      // 600000
    const int* src = ei;
    const int* dst = ei + E;

    float* out_lsm = (float*)d_out;                    // [N,40]
    float* x_emb   = (float*)d_out + (size_t)N * ODIM; // [N,128]

    // ---- workspace bump allocator (256 B aligned slots) ----
    char* w = (char*)d_ws;
    size_t off = 0;
    auto alloc = [&](size_t bytes) {
        void* p = w + off;
        off = (off + bytes + 255) & ~(size_t)255;
        return p;
    };
    int* count        = (int*)alloc((size_t)N * 4);
    int* rowptr       = (int*)alloc((size_t)(N + 1) * 4);
    int* cursor       = (int*)alloc((size_t)N * 4);
    int* csr          = (int*)alloc((size_t)E * 4);
    float* dinv       = (float*)alloc((size_t)N * 4);
    int* chunkSums    = (int*)alloc((size_t)NBLK * 4);
    unsigned* bar     = (unsigned*)alloc(256);
    unsigned short* Wt1 = (unsigned short*)alloc(128 * 128 * 2);
    unsigned short* Wt2 = (unsigned short*)alloc(128 * 128 * 2);
    unsigned short* xbf  = (unsigned short*)alloc((size_t)N * 128 * 2);
    unsigned short* bufA = (unsigned short*)alloc((size_t)N * 128 * 2);
    unsigned short* bufB = (unsigned short*)alloc((size_t)N * 128 * 2);

    hipMemsetAsync(bar, 0, sizeof(unsigned), stream);
    gcn_mega_k<<<NBLK, NTHR, 0, stream>>>(
        x, src, dst, W1, b1, W2, b2, Wl, bl,
        count, rowptr, cursor, csr, dinv, chunkSums, bar,
        Wt1, Wt2, xbf, bufA, bufB, x_emb, out_lsm, N, E);
}

// Round 8
// 266.281 us; speedup vs baseline: 3.0276x; 3.0276x over previous
//
#include <hip/hip_runtime.h>
#include <hip/hip_bf16.h>
#include <math.h>
#include <type_traits>

#define FDIM 128     // in/hid feature dim
#define ODIM 40      // output classes

typedef __attribute__((ext_vector_type(8))) short bf16x8;
typedef __attribute__((ext_vector_type(4))) float f32x4;

// ---- bf16 pack/unpack helpers (manual, RNE) --------------------------------
__device__ __forceinline__ float bf_lo(unsigned v) { return __uint_as_float(v << 16); }
__device__ __forceinline__ float bf_hi(unsigned v) { return __uint_as_float(v & 0xFFFF0000u); }
__device__ __forceinline__ unsigned f2bf(float f) {   // round-to-nearest-even
    unsigned u = __float_as_uint(f);
    return (u + 0x7FFFu + ((u >> 16) & 1u)) >> 16;
}

// ---------------------------------------------------------------------------
// 1) count in-degrees (dst atomics) + convert W1/W2 -> Wt bf16 (fused)
// ---------------------------------------------------------------------------
__global__ void count_conv_k(const int* __restrict__ dst, int* __restrict__ count, int E,
                             const float* __restrict__ W1, const float* __restrict__ W2,
                             unsigned short* __restrict__ Wt1, unsigned short* __restrict__ Wt2) {
    int e = blockIdx.x * 256 + threadIdx.x;
    if (e < E) atomicAdd(&count[dst[e]], 1);
    if (e < 2 * 16384) {                       // first 128 blocks also transpose weights
        const float* W = (e < 16384) ? W1 : W2;
        unsigned short* Wt = (e < 16384) ? Wt1 : Wt2;
        int j = e & 16383;
        int k = j >> 7, n = j & 127;
        Wt[n * 128 + k] = (unsigned short)f2bf(W[k * 128 + n]);
    }
}

// ---------------------------------------------------------------------------
// 2) single-pass decoupled-lookback exclusive scan over count[N] (1024/block)
//    -> rowptr, cursor, dinv, rowptr[N]. states[b] = flag<<62 | inclusive/agg.
//    flag: 1 = block aggregate available, 2 = inclusive prefix available.
//    Blocks only wait on EARLIER blocks' published words -> deadlock-free.
// ---------------------------------------------------------------------------
#define FLG_AGG (1ull << 62)
#define FLG_INC (2ull << 62)
__global__ __launch_bounds__(256) void scan_lookback_k(
        const int* __restrict__ count, unsigned long long* __restrict__ states,
        int* __restrict__ rowptr, int* __restrict__ cursor,
        float* __restrict__ dinv, int n, int nblocks) {
    __shared__ int ts[256];
    __shared__ int s_prefix;
    const int b = blockIdx.x, tid = threadIdx.x;
    const int base = b * 1024 + tid * 4;
    int c[4];
    int s = 0;
#pragma unroll
    for (int j = 0; j < 4; ++j) {
        int i = base + j;
        c[j] = (i < n) ? count[i] : 0;
        s += c[j];
    }
    ts[tid] = s;
    __syncthreads();
    for (int off = 1; off < 256; off <<= 1) {   // Hillis-Steele inclusive
        int v = (tid >= off) ? ts[tid - off] : 0;
        __syncthreads();
        ts[tid] += v;
        __syncthreads();
    }
    const int total = ts[255];
    if (tid == 0) {
        if (b == 0) {
            __hip_atomic_store(&states[0], FLG_INC | (unsigned long long)total,
                               __ATOMIC_RELAXED, __HIP_MEMORY_SCOPE_AGENT);
            s_prefix = 0;
        } else {
            __hip_atomic_store(&states[b], FLG_AGG | (unsigned long long)total,
                               __ATOMIC_RELAXED, __HIP_MEMORY_SCOPE_AGENT);
            int prefix = 0;
            int j = b - 1;
            while (true) {
                unsigned long long v = __hip_atomic_load(&states[j], __ATOMIC_RELAXED,
                                                         __HIP_MEMORY_SCOPE_AGENT);
                unsigned long long f = v >> 62;
                if (f == 2ull) { prefix += (int)(v & 0xFFFFFFFFull); break; }
                if (f == 1ull) { prefix += (int)(v & 0xFFFFFFFFull); --j; }
                else __builtin_amdgcn_s_sleep(1);
            }
            __hip_atomic_store(&states[b], FLG_INC | (unsigned long long)(prefix + total),
                               __ATOMIC_RELAXED, __HIP_MEMORY_SCOPE_AGENT);
            s_prefix = prefix;
        }
    }
    __syncthreads();
    int excl = s_prefix + ts[tid] - s;
#pragma unroll
    for (int j = 0; j < 4; ++j) {
        int i = base + j;
        if (i < n) {
            rowptr[i] = excl;
            cursor[i] = excl;
            dinv[i] = rsqrtf((float)(c[j] + 1));
        }
        excl += c[j];
    }
    if (b == nblocks - 1 && tid == 255) rowptr[n] = s_prefix + total;
}

// ---------------------------------------------------------------------------
// 3) fill CSR: src ids grouped by dst
// ---------------------------------------------------------------------------
__global__ void fill_csr_k(const int* __restrict__ src, const int* __restrict__ dst,
                           int* __restrict__ cursor, int* __restrict__ csr_src, int E) {
    int e = blockIdx.x * blockDim.x + threadIdx.x;
    if (e < E) {
        int d = dst[e];
        int p = atomicAdd(&cursor[d], 1);
        csr_src[p] = src[e];
    }
}

// ---------------------------------------------------------------------------
// 4) MFMA GEMM: Cb[M,128](bf16) = (A[M,128] @ W) * dinv[row]
//    Wt is W transposed, bf16 [n][k]. 64-row tile per 256-thread block.
//    Whole K=128 staged to LDS once; 4 waves x 32 cols; 16x16x32 bf16 MFMA.
// ---------------------------------------------------------------------------
template <typename AT>
__global__ __launch_bounds__(256) void mfma_gemm_k(const AT* __restrict__ A,
                                                   const unsigned short* __restrict__ Wt,
                                                   const float* __restrict__ dinv,
                                                   unsigned short* __restrict__ Cb, int M) {
    __shared__ unsigned short As[64][136];   // row stride 272 B = 4 banks mod 32
    __shared__ unsigned short Bs[128][136];

    const int tid = threadIdx.x;
    const int row0 = blockIdx.x * 64;

    // ---- stage A (64 x 128) ----
    if constexpr (std::is_same_v<AT, float>) {
#pragma unroll
        for (int i = 0; i < 8; ++i) {        // 64 rows * 32 float4 = 2048
            int fidx = i * 256 + tid;
            int r = fidx >> 5, kq = fidx & 31;
            float4 v = make_float4(0.f, 0.f, 0.f, 0.f);
            int grow = row0 + r;
            if (grow < M) v = *(const float4*)&A[(size_t)grow * 128 + kq * 4];
            unsigned lo = f2bf(v.x) | (f2bf(v.y) << 16);
            unsigned hi = f2bf(v.z) | (f2bf(v.w) << 16);
            *(uint2*)&As[r][kq * 4] = make_uint2(lo, hi);
        }
    } else {
#pragma unroll
        for (int i = 0; i < 4; ++i) {        // 64 rows * 16 uint4 = 1024
            int fidx = i * 256 + tid;
            int r = fidx >> 4, kq = fidx & 15;
            uint4 v = make_uint4(0, 0, 0, 0);
            int grow = row0 + r;
            if (grow < M) v = *(const uint4*)&A[(size_t)grow * 128 + kq * 8];
            *(uint4*)&As[r][kq * 8] = v;
        }
    }
    // ---- stage B (128 x 128) ----
#pragma unroll
    for (int i = 0; i < 8; ++i) {            // 128 rows * 16 uint4 = 2048
        int fidx = i * 256 + tid;
        int r = fidx >> 4, kq = fidx & 15;
        *(uint4*)&Bs[r][kq * 8] = *(const uint4*)&Wt[(size_t)r * 128 + kq * 8];
    }
    __syncthreads();

    // ---- compute ----
    const int lane = tid & 63;
    const int wv = tid >> 6;       // wave 0..3 -> cols wv*32 .. +31
    const int n0 = wv * 32;
    const int mrow = lane & 15;
    const int quad = lane >> 4;

    f32x4 acc[4][2];
#pragma unroll
    for (int mt = 0; mt < 4; ++mt)
#pragma unroll
        for (int nt = 0; nt < 2; ++nt) acc[mt][nt] = (f32x4){0.f, 0.f, 0.f, 0.f};

#pragma unroll
    for (int kk = 0; kk < 128; kk += 32) {
        int ko = kk + quad * 8;
        bf16x8 af[4], bfr[2];
#pragma unroll
        for (int mt = 0; mt < 4; ++mt) af[mt] = *(const bf16x8*)&As[mt * 16 + mrow][ko];
#pragma unroll
        for (int nt = 0; nt < 2; ++nt) bfr[nt] = *(const bf16x8*)&Bs[n0 + nt * 16 + mrow][ko];
#pragma unroll
        for (int mt = 0; mt < 4; ++mt)
#pragma unroll
            for (int nt = 0; nt < 2; ++nt)
                acc[mt][nt] = __builtin_amdgcn_mfma_f32_16x16x32_bf16(af[mt], bfr[nt], acc[mt][nt], 0, 0, 0);
    }

    // ---- epilogue: C layout col=lane&15, row=quad*4+reg ----
#pragma unroll
    for (int mt = 0; mt < 4; ++mt) {
#pragma unroll
        for (int reg = 0; reg < 4; ++reg) {
            int grow = row0 + mt * 16 + quad * 4 + reg;
            if (grow < M) {
                float sc = dinv[grow];
#pragma unroll
                for (int nt = 0; nt < 2; ++nt) {
                    int col = n0 + nt * 16 + mrow;
                    Cb[(size_t)grow * 128 + col] = (unsigned short)f2bf(acc[mt][nt][reg] * sc);
                }
            }
        }
    }
}

// ---------------------------------------------------------------------------
// 5) aggregate: out[d,:] = act( dinv[d]*(g[d,:] + sum_{s in N(d)} g[s,:]) + b )
//    one 64-lane wave per dst node; lane owns 2 channels (bf16x2); unroll 8.
// ---------------------------------------------------------------------------
template <bool RELU, bool OUT_BF16>
__global__ __launch_bounds__(64) void aggregate_k(const unsigned* __restrict__ g,
                                                  const float* __restrict__ dinv,
                                                  const int* __restrict__ rowptr,
                                                  const int* __restrict__ csr_src,
                                                  const float* __restrict__ bias,
                                                  void* __restrict__ outv, int n) {
    const int d = blockIdx.x;
    const int c = threadIdx.x;            // lane: channels 2c, 2c+1
    unsigned self = g[(size_t)d * 64 + c];
    float ax = bf_lo(self), ay = bf_hi(self);
    int e = rowptr[d], end = rowptr[d + 1];
    for (; e + 7 < end; e += 8) {
        int s0 = csr_src[e],     s1 = csr_src[e + 1], s2 = csr_src[e + 2], s3 = csr_src[e + 3];
        int s4 = csr_src[e + 4], s5 = csr_src[e + 5], s6 = csr_src[e + 6], s7 = csr_src[e + 7];
        unsigned v0 = g[(size_t)s0 * 64 + c], v1 = g[(size_t)s1 * 64 + c];
        unsigned v2 = g[(size_t)s2 * 64 + c], v3 = g[(size_t)s3 * 64 + c];
        unsigned v4 = g[(size_t)s4 * 64 + c], v5 = g[(size_t)s5 * 64 + c];
        unsigned v6 = g[(size_t)s6 * 64 + c], v7 = g[(size_t)s7 * 64 + c];
        ax += (bf_lo(v0) + bf_lo(v1)) + (bf_lo(v2) + bf_lo(v3))
            + (bf_lo(v4) + bf_lo(v5)) + (bf_lo(v6) + bf_lo(v7));
        ay += (bf_hi(v0) + bf_hi(v1)) + (bf_hi(v2) + bf_hi(v3))
            + (bf_hi(v4) + bf_hi(v5)) + (bf_hi(v6) + bf_hi(v7));
    }
    for (; e < end; ++e) {
        unsigned v = g[(size_t)csr_src[e] * 64 + c];
        ax += bf_lo(v);
        ay += bf_hi(v);
    }
    float sc = dinv[d];
    float ox = fmaf(sc, ax, bias[2 * c]);
    float oy = fmaf(sc, ay, bias[2 * c + 1]);
    if (RELU) { ox = fmaxf(ox, 0.f); oy = fmaxf(oy, 0.f); }
    if constexpr (OUT_BF16) {
        ((unsigned*)outv)[(size_t)d * 64 + c] = f2bf(ox) | (f2bf(oy) << 16);
    } else {
        ((float2*)outv)[(size_t)d * 64 + c] = make_float2(ox, oy);
    }
}

// ---------------------------------------------------------------------------
// 6) logits = x_emb @ Wl + bl; log_softmax over 40 cols.
// ---------------------------------------------------------------------------
__global__ __launch_bounds__(256) void logits_lsm_k(const float* __restrict__ xe,
                                                    const float* __restrict__ Wl,
                                                    const float* __restrict__ bl,
                                                    float* __restrict__ out, int M) {
    __shared__ float sW[128 * 40];
    __shared__ float sX[32][132];
    __shared__ float sB[40];
    const int tid = threadIdx.x;
    const int row0 = blockIdx.x * 32;

    for (int i = tid; i < (128 * 40) / 4; i += 256)
        ((float4*)sW)[i] = ((const float4*)Wl)[i];
    if (tid < 40) sB[tid] = bl[tid];
    for (int i = tid; i < 32 * 32; i += 256) {
        int r = i >> 5, cq = i & 31;
        float4 v = make_float4(0.f, 0.f, 0.f, 0.f);
        if (row0 + r < M) v = *(const float4*)&xe[(size_t)(row0 + r) * 128 + cq * 4];
        *(float4*)&sX[r][cq * 4] = v;
    }
    __syncthreads();

    const int g = tid >> 3;  // local row 0..31
    const int l = tid & 7;   // lane-in-row
    const int row = row0 + g;
    float acc[5] = {0.f, 0.f, 0.f, 0.f, 0.f};
    for (int k = 0; k < 128; ++k) {
        float xv = sX[g][k];
        const float* w = &sW[k * 40 + l * 5];
#pragma unroll
        for (int j = 0; j < 5; ++j) acc[j] = fmaf(xv, w[j], acc[j]);
    }
#pragma unroll
    for (int j = 0; j < 5; ++j) acc[j] += sB[l * 5 + j];

    float m = acc[0];
#pragma unroll
    for (int j = 1; j < 5; ++j) m = fmaxf(m, acc[j]);
#pragma unroll
    for (int off = 1; off < 8; off <<= 1) m = fmaxf(m, __shfl_xor(m, off));
    float s = 0.f;
#pragma unroll
    for (int j = 0; j < 5; ++j) s += expf(acc[j] - m);
#pragma unroll
    for (int off = 1; off < 8; off <<= 1) s += __shfl_xor(s, off);
    float lse = m + logf(s);
    if (row < M) {
#pragma unroll
        for (int j = 0; j < 5; ++j) out[(size_t)row * 40 + l * 5 + j] = acc[j] - lse;
    }
}

// ---------------------------------------------------------------------------
// launch
// ---------------------------------------------------------------------------
extern "C" void kernel_launch(void* const* d_in, const int* in_sizes, int n_in,
                              void* d_out, int out_size, void* d_ws, size_t ws_size,
                              hipStream_t stream) {
    const float* x  = (const float*)d_in[0];
    const int*   ei = (const int*)d_in[1];
    const float* W1 = (const float*)d_in[2];
    const float* b1 = (const float*)d_in[3];
    const float* W2 = (const float*)d_in[4];
    const float* b2 = (const float*)d_in[5];
    const float* Wl = (const float*)d_in[6];
    const float* bl = (const float*)d_in[7];

    const int N = in_sizes[0] / FDIM;   // 50000
    const int E = in_sizes[1] / 2;      // 600000
    const int* src = ei;
    const int* dst = ei + E;

    float* out_lsm = (float*)d_out;                    // [N,40]
    float* x_emb   = (float*)d_out + (size_t)N * ODIM; // [N,128]

    // ---- workspace bump allocator (256 B aligned slots) ----
    char* w = (char*)d_ws;
    size_t off = 0;
    auto alloc = [&](size_t bytes) {
        void* p = w + off;
        off = (off + bytes + 255) & ~(size_t)255;
        return p;
    };
    int* count = (int*)alloc((size_t)N * 4);
    unsigned long long* states = (unsigned long long*)alloc(64 * 8);  // contiguous after count
    int* rowptr = (int*)alloc((size_t)(N + 1) * 4);
    int* cursor = (int*)alloc((size_t)N * 4);
    int* csr    = (int*)alloc((size_t)E * 4);
    float* dinv = (float*)alloc((size_t)N * 4);
    unsigned short* Wt1 = (unsigned short*)alloc(128 * 128 * 2);
    unsigned short* Wt2 = (unsigned short*)alloc(128 * 128 * 2);
    unsigned* bufA = (unsigned*)alloc((size_t)N * 64 * 4);
    unsigned* bufB = (unsigned*)alloc((size_t)N * 64 * 4);

    // zero count + states in ONE memset (they are adjacent slots)
    size_t zlen = ((char*)states - (char*)count) + 64 * 8;
    hipMemsetAsync(count, 0, zlen, stream);

    const int nsc = (N + 1023) / 1024;            // 49 scan blocks (<=64 states)
    count_conv_k<<<(E + 255) / 256, 256, 0, stream>>>(dst, count, E, W1, W2, Wt1, Wt2);
    scan_lookback_k<<<nsc, 256, 0, stream>>>(count, states, rowptr, cursor, dinv, N, nsc);
    fill_csr_k<<<(E + 255) / 256, 256, 0, stream>>>(src, dst, cursor, csr, E);

    int gblocks = (N + 63) / 64;
    // layer 1
    mfma_gemm_k<float><<<gblocks, 256, 0, stream>>>(x, Wt1, dinv, (unsigned short*)bufA, N);
    aggregate_k<true, true><<<N, 64, 0, stream>>>(bufA, dinv, rowptr, csr, b1, bufB, N);
    // layer 2
    mfma_gemm_k<unsigned short><<<gblocks, 256, 0, stream>>>(
        (const unsigned short*)bufB, Wt2, dinv, (unsigned short*)bufA, N);
    aggregate_k<false, false><<<N, 64, 0, stream>>>(bufA, dinv, rowptr, csr, b2, x_emb, N);
    // head
    logits_lsm_k<<<(N + 31) / 32, 256, 0, stream>>>(x_emb, Wl, bl, out_lsm, N);
}